// Round 3
// baseline (698.327 us; speedup 1.0000x reference)
//
#include <hip/hip_runtime.h>
#include <stdint.h>

// Problem constants (fixed by the reference): N=7+1 blocks, B*L=8192, D=2048.
#define NB   8
#define DDIM 2048
#define BLK  256          // 4 waves per WG, one ROW per WAVE (no cross-wave coupling)

typedef float v4f __attribute__((ext_vector_type(4)));

// Two-pass, wave-independent design:
//   Pass 1: stream V once from HBM, accumulate per-block sum-of-squares (ss)
//           and proj-dot (dt). Nothing held in registers.
//   Reduce: 64-lane butterfly within the wave (no __syncthreads, no LDS).
//   Pass 2: re-read V (should hit L3: in-flight rows are capped at
//           12 waves/CU * 256 CU * 64 KB = 201 MB < 256 MB Infinity Cache)
//           with nontemporal loads, weighted-sum, nontemporal store.
// Occupancy deliberately capped at 3 WGs/CU via 48 KB dummy dynamic LDS to
// stay under the L3 LRU cliff.
__global__ __launch_bounds__(BLK) void attn_residual_kernel(
    const float* __restrict__ blocks,   // [7][BL][D] f32
    const float* __restrict__ partial,  // [BL][D] f32
    const float* __restrict__ scale,    // [D] f32
    const float* __restrict__ proj,     // [D] f32
    float*       __restrict__ out,      // [BL][D] f32
    int BL)
{
    const int lane  = threadIdx.x & 63;
    const int wv    = threadIdx.x >> 6;
    const int rowid = (blockIdx.x << 2) | wv;     // one row per wave
    const size_t row     = (size_t)rowid * DDIM;
    const size_t nstride = (size_t)BL * DDIM;

    const float* bases[NB];
    #pragma unroll
    for (int n = 0; n < NB - 1; ++n) bases[n] = blocks + (size_t)n * nstride + row;
    bases[NB - 1] = partial + row;

    float ss[NB], dt[NB];
    #pragma unroll
    for (int n = 0; n < NB; ++n) { ss[n] = 0.f; dt[n] = 0.f; }

    const int d0 = lane << 2;                     // lane*4; wave covers 256 floats/j

    // ---- Pass 1: stream V, accumulate ss and dt ----
    #pragma unroll 2
    for (int j = 0; j < 8; ++j) {
        const int d = (j << 8) + d0;              // j*256 + lane*4
        const v4f pr = *(const v4f*)(proj  + d);  // 8 KB, L1-hot across WGs
        const v4f sc = *(const v4f*)(scale + d);
        const v4f p  = pr * sc;
        #pragma unroll
        for (int n = 0; n < NB; ++n) {
            const v4f x = *(const v4f*)(bases[n] + d);
            ss[n] = fmaf(x.x, x.x, fmaf(x.y, x.y, fmaf(x.z, x.z, fmaf(x.w, x.w, ss[n]))));
            dt[n] = fmaf(p.x, x.x, fmaf(p.y, x.y, fmaf(p.z, x.z, fmaf(p.w, x.w, dt[n]))));
        }
    }

    // ---- Wave-wide butterfly reduction (result broadcast to all 64 lanes) ----
    #pragma unroll
    for (int n = 0; n < NB; ++n) {
        float a = ss[n], b = dt[n];
        #pragma unroll
        for (int off = 1; off < 64; off <<= 1) {
            a += __shfl_xor(a, off, 64);
            b += __shfl_xor(b, off, 64);
        }
        ss[n] = a; dt[n] = b;
    }

    // ---- Softmax over the N=8 axis (redundant per lane, trivial) ----
    float w[NB], m = -1e30f;
    #pragma unroll
    for (int n = 0; n < NB; ++n) {
        const float rms = sqrtf(ss[n] * (1.0f / DDIM) + 1e-6f);
        w[n] = dt[n] / rms;
        m = fmaxf(m, w[n]);
    }
    float denom = 0.f;
    #pragma unroll
    for (int n = 0; n < NB; ++n) { w[n] = __expf(w[n] - m); denom += w[n]; }
    const float inv = 1.0f / denom;
    #pragma unroll
    for (int n = 0; n < NB; ++n) w[n] *= inv;

    // ---- Pass 2: re-read V (L3-resident), weighted sum, stream out ----
    #pragma unroll 2
    for (int j = 0; j < 8; ++j) {
        const int d = (j << 8) + d0;
        v4f o = {0.f, 0.f, 0.f, 0.f};
        #pragma unroll
        for (int n = 0; n < NB; ++n) {
            const v4f x = __builtin_nontemporal_load((const v4f*)(bases[n] + d));
            o.x = fmaf(w[n], x.x, o.x);
            o.y = fmaf(w[n], x.y, o.y);
            o.z = fmaf(w[n], x.z, o.z);
            o.w = fmaf(w[n], x.w, o.w);
        }
        __builtin_nontemporal_store(o, (v4f*)(out + row + d));
    }
}

extern "C" void kernel_launch(void* const* d_in, const int* in_sizes, int n_in,
                              void* d_out, int out_size, void* d_ws, size_t ws_size,
                              hipStream_t stream) {
    const float* blocks  = (const float*)d_in[0];
    const float* partial = (const float*)d_in[1];
    const float* scale   = (const float*)d_in[2];
    const float* proj    = (const float*)d_in[3];
    float* out = (float*)d_out;

    const int BL = in_sizes[1] / DDIM;            // B*L = 8192
    // 48 KB dummy dynamic LDS: caps residency at 3 WGs/CU (12 waves/CU)
    // so in-flight pass-1 data (201 MB) stays under the 256 MB L3.
    attn_residual_kernel<<<dim3(BL / 4), dim3(BLK), 48 * 1024, stream>>>(
        blocks, partial, scale, proj, out, BL);
}